// Round 6
// baseline (363.410 us; speedup 1.0000x reference)
//
#include <hip/hip_runtime.h>

typedef unsigned short u16;
typedef __attribute__((ext_vector_type(8))) __bf16 bf16x8;
typedef __attribute__((ext_vector_type(8))) unsigned short ushort8;
typedef __attribute__((ext_vector_type(4))) float f32x4;

#define MFMA16(a, b, c) __builtin_amdgcn_mfma_f32_16x16x32_bf16((a), (b), (c), 0, 0, 0)

__device__ __forceinline__ u16 f2bf(float f) {
  union { __bf16 h; u16 u; } cv;
  cv.h = (__bf16)f;
  return cv.u;
}

__device__ __forceinline__ void async16(const u16* g, u16* l) {
  __builtin_amdgcn_global_load_lds(
      (const __attribute__((address_space(1))) void*)g,
      (__attribute__((address_space(3))) void*)l, 16, 0, 0);
}

// ---------------- weight transpose fp32 [K][N] -> bf16 [N][K] ----------------
__global__ __launch_bounds__(256)
void transpose_bf16(const float* __restrict__ W, u16* __restrict__ Wt, int K, int N) {
  __shared__ float t[32][33];
  const int n0 = blockIdx.x * 32, k0 = blockIdx.y * 32;
  const int tx = threadIdx.x, ty = threadIdx.y;
  #pragma unroll
  for (int i = 0; i < 32; i += 8)
    t[ty + i][tx] = W[(size_t)(k0 + ty + i) * N + n0 + tx];
  __syncthreads();
  #pragma unroll
  for (int i = 0; i < 32; i += 8)
    Wt[(size_t)(n0 + ty + i) * K + k0 + tx] = f2bf(t[tx][ty + i]);
}

// ---------------- bf16 transpose for V: [B*H][2048][64] -> [B*H][64][2048] ----------------
__global__ __launch_bounds__(256)
void transpose_v(const u16* __restrict__ v, u16* __restrict__ vt) {
  __shared__ u16 t[64][72];
  const int bh = blockIdx.y, t0 = blockIdx.x * 64;
  const int tid = threadIdx.x;
  #pragma unroll
  for (int s = 0; s < 2; ++s) {
    const int idx = tid + s * 256;
    const int row = idx >> 3, ch = idx & 7;
    ushort8 d = *(const ushort8*)(v + ((size_t)bh * 2048 + t0 + row) * 64 + ch * 8);
    #pragma unroll
    for (int e = 0; e < 8; ++e) t[ch * 8 + e][row] = d[e];
  }
  __syncthreads();
  #pragma unroll
  for (int s = 0; s < 2; ++s) {
    const int idx = tid + s * 256;
    const int drow = idx >> 3, ch = idx & 7;
    ushort8 o = *(const ushort8*)(&t[drow][ch * 8]);
    *(ushort8*)(vt + ((size_t)bh * 64 + drow) * 2048 + t0 + ch * 8) = o;
  }
}

// ---------------- layernorm fp32 [4096][1024] -> bf16 ----------------
__global__ __launch_bounds__(256)
void ln_bf16(const float* __restrict__ X, const float* __restrict__ w,
             const float* __restrict__ bia, u16* __restrict__ out) {
  const int row = blockIdx.x, tid = threadIdx.x;
  const float4 v = ((const float4*)(X + (size_t)row * 1024))[tid];
  float s = v.x + v.y + v.z + v.w;
  float s2 = v.x * v.x + v.y * v.y + v.z * v.z + v.w * v.w;
  #pragma unroll
  for (int o = 32; o > 0; o >>= 1) { s += __shfl_down(s, o); s2 += __shfl_down(s2, o); }
  __shared__ float red[8];
  const int wv = tid >> 6, lane = tid & 63;
  if (lane == 0) { red[wv] = s; red[4 + wv] = s2; }
  __syncthreads();
  s = red[0] + red[1] + red[2] + red[3];
  s2 = red[4] + red[5] + red[6] + red[7];
  const float mean = s * (1.f / 1024.f);
  const float var = s2 * (1.f / 1024.f) - mean * mean;
  const float rstd = rsqrtf(var + 1e-5f);
  const float4 wv4 = ((const float4*)w)[tid];
  const float4 bv4 = ((const float4*)bia)[tid];
  ushort4 o;
  o.x = f2bf((v.x - mean) * rstd * wv4.x + bv4.x);
  o.y = f2bf((v.y - mean) * rstd * wv4.y + bv4.y);
  o.z = f2bf((v.z - mean) * rstd * wv4.z + bv4.z);
  o.w = f2bf((v.w - mean) * rstd * wv4.w + bv4.w);
  ((ushort4*)(out + (size_t)row * 1024))[tid] = o;
}

// ---------------- 128-tile GEMM (kept for split-K cases): C = A * Bt^T ----------------
// MODE 4: outF[z*M*N + ...] = acc (fp32 partial, split-K)
template <int MODE>
__global__ __launch_bounds__(256)
void gemm_bt(const u16* __restrict__ A, const u16* __restrict__ Bt,
             const float* __restrict__ bias, const float* __restrict__ resid,
             float* __restrict__ outF, u16* __restrict__ outB,
             u16* __restrict__ qo, u16* __restrict__ ko, u16* __restrict__ vo,
             int M, int N, int K, int kSlice) {
  __shared__ u16 As[128 * 64];
  __shared__ u16 Bs[128 * 64];
  const int tid = threadIdx.x;
  const int lane = tid & 63, wv = tid >> 6;
  const int l16 = lane & 15, quad = lane >> 4;
  const int wr = wv >> 1, wc = wv & 1;
  const int m0 = blockIdx.y * 128, n0 = blockIdx.x * 128;
  const int kBegin = blockIdx.z * kSlice, kEnd = kBegin + kSlice;
  const int srow = lane >> 3;
  const int sch = (lane & 7) ^ srow;

  f32x4 acc[4][4];
  const f32x4 fz = {0.f, 0.f, 0.f, 0.f};
  #pragma unroll
  for (int i = 0; i < 4; ++i)
    #pragma unroll
    for (int j = 0; j < 4; ++j) acc[i][j] = fz;

  for (int k0 = kBegin; k0 < kEnd; k0 += 64) {
    __syncthreads();
    #pragma unroll
    for (int s = 0; s < 4; ++s) {
      const int R = wv * 32 + s * 8;
      async16(A + (size_t)(m0 + R + srow) * K + k0 + sch * 8, As + R * 64);
      async16(Bt + (size_t)(n0 + R + srow) * K + k0 + sch * 8, Bs + R * 64);
    }
    __builtin_amdgcn_s_waitcnt(0xF70);  // vmcnt(0)
    __syncthreads();
    #pragma unroll
    for (int h = 0; h < 2; ++h) {
      bf16x8 af[4], bfr[4];
      #pragma unroll
      for (int i = 0; i < 4; ++i) {
        const int row = wr * 64 + i * 16 + l16;
        af[i] = *(const bf16x8*)(As + row * 64 + (((h * 4 + quad) ^ (l16 & 7)) * 8));
      }
      #pragma unroll
      for (int j = 0; j < 4; ++j) {
        const int row = wc * 64 + j * 16 + l16;
        bfr[j] = *(const bf16x8*)(Bs + row * 64 + (((h * 4 + quad) ^ (l16 & 7)) * 8));
      }
      #pragma unroll
      for (int i = 0; i < 4; ++i)
        #pragma unroll
        for (int j = 0; j < 4; ++j)
          acc[i][j] = MFMA16(af[i], bfr[j], acc[i][j]);
    }
  }

  #pragma unroll
  for (int i = 0; i < 4; ++i) {
    #pragma unroll
    for (int j = 0; j < 4; ++j) {
      const int col = n0 + wc * 64 + j * 16 + l16;
      #pragma unroll
      for (int r = 0; r < 4; ++r) {
        const int row = m0 + wr * 64 + i * 16 + quad * 4 + r;
        outF[(size_t)blockIdx.z * M * N + (size_t)row * N + col] = acc[i][j][r];
      }
    }
  }
}

// ---------------- 256x256 GEMM, BK=32, 4-buffer depth-3 counted pipeline ----------------
// K-tile k lives in buf[k&3] (As/Bs [4][256*32], 128 KiB). Loop at tile k:
//   stage(k+3) -> 12 ds_read_b128 + 32 MFMA -> vmcnt(8) [k+1 landed, issued 3 tiles
//   (~750+ cyc) ago; k+2,k+3 STAY IN FLIGHT across the barrier] -> s_barrier.
// Never drains mid-loop (T4); one barrier per K-tile. WAR ledger: stage(k+3) targets
// buf[(k-1)&3], all reads of which completed before the end-of-(k-1) barrier, and the
// stage is issued after it. Swizzle: LDS slot l&3 holds global chunk (l&3)^f(row),
// f(r)=(r>>1)&3, via pre-swizzled global source (gload_lds dest stays linear); read
// applies the same XOR -> 2-way bank conflict (free).
// MODE 0: qkv scatter (+bias) -> qo/ko/vo.  MODE 2: outB = gelu(acc+bias) bf16.
template <int MODE>
__global__ __launch_bounds__(512)
void gemm256(const u16* __restrict__ A, const u16* __restrict__ Bt,
             const float* __restrict__ bias, u16* __restrict__ outB,
             u16* __restrict__ qo, u16* __restrict__ ko, u16* __restrict__ vo,
             int M, int N, int K) {
  __shared__ u16 As[4][256 * 32];
  __shared__ u16 Bs[4][256 * 32];
  const int tid = threadIdx.x;
  const int lane = tid & 63, wv = tid >> 6;      // 8 waves
  const int l16 = lane & 15, quad = lane >> 4;
  const int wr = wv >> 2, wc = wv & 3;            // 2 x 4 wave grid, 128x64 out/wave
  // XCD-aware bijective swizzle (grid % 8 == 0)
  const int nwg = gridDim.x, cpx = nwg >> 3;
  const int bid = (int)blockIdx.x;
  const int swz = (bid & 7) * cpx + (bid >> 3);
  const int nbx = N >> 8;
  const int m0 = (swz / nbx) * 256, n0 = (swz % nbx) * 256;
  // staging lane constants: lane l -> row offset l>>2, slot l&3
  const int sR = lane >> 2;
  const int sc = lane & 3;

  f32x4 acc[8][4];
  const f32x4 fz = {0.f, 0.f, 0.f, 0.f};
  #pragma unroll
  for (int i = 0; i < 8; ++i)
    #pragma unroll
    for (int j = 0; j < 4; ++j) acc[i][j] = fz;

  auto stage = [&](int kt) {
    const int p = kt & 3;
    #pragma unroll
    for (int i = 0; i < 2; ++i) {
      const int r = i * 128 + wv * 16 + sR;            // local row 0..255
      const int ch = sc ^ ((r >> 1) & 3);              // pre-swizzled source chunk
      async16(A + (size_t)(m0 + r) * K + kt * 32 + ch * 8,
              &As[p][(i * 128 + wv * 16) * 32]);
      async16(Bt + (size_t)(n0 + r) * K + kt * 32 + ch * 8,
              &Bs[p][(i * 128 + wv * 16) * 32]);
    }
  };
  auto ldf = [&](const u16* base, int r) {
    return *(const bf16x8*)(base + r * 32 + ((quad ^ ((r >> 1) & 3)) * 8));
  };

  const int nt = K >> 5;
  // prologue: tiles 0,1,2 in flight; wait tile 0 only (counted)
  stage(0);
  stage(1);
  stage(2);
  __builtin_amdgcn_s_waitcnt(0xF78);  // vmcnt(8): tile 0 landed, 1-2 in flight
  __builtin_amdgcn_s_barrier();
  __builtin_amdgcn_sched_barrier(0);

  for (int kt = 0; kt < nt; ++kt) {
    if (kt + 3 < nt) stage(kt + 3);
    const u16* Ap = As[kt & 3];
    const u16* Bp = Bs[kt & 3];
    bf16x8 b[4];
    #pragma unroll
    for (int j = 0; j < 4; ++j) b[j] = ldf(Bp, wc * 64 + j * 16 + l16);
    __builtin_amdgcn_s_setprio(1);
    #pragma unroll
    for (int i = 0; i < 8; ++i) {
      bf16x8 a = ldf(Ap, wr * 128 + i * 16 + l16);
      #pragma unroll
      for (int j = 0; j < 4; ++j) acc[i][j] = MFMA16(a, b[j], acc[i][j]);
    }
    __builtin_amdgcn_s_setprio(0);
    // counted wait: tile kt+1 landed; deeper prefetch stays in flight
    if (kt + 3 < nt)
      __builtin_amdgcn_s_waitcnt(0xF78);  // vmcnt(8)
    else if (kt + 2 < nt)
      __builtin_amdgcn_s_waitcnt(0xF74);  // vmcnt(4)
    else if (kt + 1 < nt)
      __builtin_amdgcn_s_waitcnt(0xF70);  // vmcnt(0) (tail only)
    if (kt + 1 < nt) {
      __builtin_amdgcn_s_barrier();
      __builtin_amdgcn_sched_barrier(0);
    }
  }

  // ---- epilogue
  #pragma unroll
  for (int i = 0; i < 8; ++i) {
    #pragma unroll
    for (int j = 0; j < 4; ++j) {
      const int col = n0 + wc * 64 + j * 16 + l16;
      const float bc = bias[col];
      #pragma unroll
      for (int r = 0; r < 4; ++r) {
        const int row = m0 + wr * 128 + i * 16 + quad * 4 + r;
        float v = acc[i][j][r] + bc;
        if (MODE == 0) {
          const int which = col >> 10, cc = col & 1023, hh = cc >> 6, dd = cc & 63;
          const int bb = row >> 11, t = row & 2047;
          const u16 bv = f2bf(v);
          const size_t o = ((size_t)(bb * 16 + hh) * 2048 + t) * 64 + dd;
          if (which == 0)
            qo[o] = bv;
          else if (which == 1)
            ko[o] = bv;
          else
            vo[o] = bv;
        } else {
          const float x3 = v * v * v;
          const float u = 0.7978845608028654f * (v + 0.044715f * x3);
          const float e = __expf(2.f * u);
          const float th = 1.f - 2.f / (e + 1.f);
          outB[(size_t)row * N + col] = f2bf(0.5f * v * (1.f + th));
        }
      }
    }
  }
}

// ---------------- split-K reduce: out = resid + bias + P0 + P1 ----------------
__global__ __launch_bounds__(256)
void reduce2(const float* __restrict__ P, const float* __restrict__ resid,
             const float* __restrict__ bias, float* __restrict__ out, int MN, int N) {
  const int idx4 = blockIdx.x * 256 + threadIdx.x;
  const size_t s = (size_t)MN >> 2;
  const float4 a = ((const float4*)P)[idx4];
  const float4 b = ((const float4*)P)[idx4 + s];
  const float4 r = ((const float4*)resid)[idx4];
  const float4 bb = ((const float4*)bias)[idx4 & (N / 4 - 1)];
  float4 o;
  o.x = r.x + a.x + b.x + bb.x;
  o.y = r.y + a.y + b.y + bb.y;
  o.z = r.z + a.z + b.z + bb.z;
  o.w = r.w + a.w + b.w + bb.w;
  ((float4*)out)[idx4] = o;
}

// ---------------- fused split-K reduce + layernorm ----------------
__global__ __launch_bounds__(256)
void reduce2_ln(const float* __restrict__ P, const float* __restrict__ resid,
                const float* __restrict__ bias, const float* __restrict__ lw,
                const float* __restrict__ lb, float* __restrict__ out,
                u16* __restrict__ h2, int MN) {
  const int row = blockIdx.x, tid = threadIdx.x;
  const int idx4 = row * 256 + tid;
  const size_t s4 = (size_t)MN >> 2;
  const float4 a = ((const float4*)P)[idx4];
  const float4 b = ((const float4*)P)[idx4 + s4];
  const float4 r = ((const float4*)resid)[idx4];
  const float4 bb = ((const float4*)bias)[tid];
  float4 o;
  o.x = r.x + a.x + b.x + bb.x;
  o.y = r.y + a.y + b.y + bb.y;
  o.z = r.z + a.z + b.z + bb.z;
  o.w = r.w + a.w + b.w + bb.w;
  ((float4*)out)[idx4] = o;
  float s = o.x + o.y + o.z + o.w;
  float s2 = o.x * o.x + o.y * o.y + o.z * o.z + o.w * o.w;
  #pragma unroll
  for (int of = 32; of > 0; of >>= 1) { s += __shfl_down(s, of); s2 += __shfl_down(s2, of); }
  __shared__ float red[8];
  const int wv = tid >> 6, lane = tid & 63;
  if (lane == 0) { red[wv] = s; red[4 + wv] = s2; }
  __syncthreads();
  s = red[0] + red[1] + red[2] + red[3];
  s2 = red[4] + red[5] + red[6] + red[7];
  const float mean = s * (1.f / 1024.f);
  const float var = s2 * (1.f / 1024.f) - mean * mean;
  const float rstd = rsqrtf(var + 1e-5f);
  const float4 wv4 = ((const float4*)lw)[tid];
  const float4 bv4 = ((const float4*)lb)[tid];
  ushort4 ob;
  ob.x = f2bf((o.x - mean) * rstd * wv4.x + bv4.x);
  ob.y = f2bf((o.y - mean) * rstd * wv4.y + bv4.y);
  ob.z = f2bf((o.z - mean) * rstd * wv4.z + bv4.z);
  ob.w = f2bf((o.w - mean) * rstd * wv4.w + bv4.w);
  ((ushort4*)(h2 + (size_t)row * 1024))[tid] = ob;
}

// ---------------- flash attention (causal), S^T softmax, register-P, 8-wave merged ----------------
// (round-5 proven version)
typedef union { bf16x8 v; unsigned d[4]; } PFU;

__global__ __launch_bounds__(512)
void attn(const u16* __restrict__ Q, const u16* __restrict__ Kg,
          const u16* __restrict__ Vt, u16* __restrict__ ctx) {
  __shared__ u16 Ks[2][128 * 64];  // [key][64], chunk slot s holds global chunk s^(key&7)
  __shared__ u16 Vs[64 * 128];     // [d][128], chunk slot s holds global chunk s^(d&15)
  const int pair = blockIdx.x;     // 0..7
  const int qt0 = pair, qt1 = 15 - pair;
  const int bh = blockIdx.y;
  const int b = bh >> 4, h = bh & 15;
  const int tid = threadIdx.x;
  const int lane = tid & 63, wv = tid >> 6;  // 8 waves
  const int l16 = lane & 15, quad = lane >> 4;
  const int rb = wv * 16;                    // rows rb..rb+15 of each tile
  const float S2 = 0.18033688011112042f;     // 0.125 * log2(e)
  const u16* Qb = Q + (size_t)bh * 2048 * 64;
  const u16* Kb = Kg + (size_t)bh * 2048 * 64;
  const u16* Vb = Vt + (size_t)bh * 64 * 2048;

  bf16x8 qf[2][2];
  #pragma unroll
  for (int t = 0; t < 2; ++t)
    #pragma unroll
    for (int c = 0; c < 2; ++c)
      qf[t][c] = *(const bf16x8*)(Qb + (size_t)((t ? qt1 : qt0) * 128 + rb + l16) * 64 +
                                  c * 32 + quad * 8);

  f32x4 octx[2][4];
  const f32x4 fz = {0.f, 0.f, 0.f, 0.f};
  #pragma unroll
  for (int t = 0; t < 2; ++t)
    #pragma unroll
    for (int jd = 0; jd < 4; ++jd) octx[t][jd] = fz;
  float mi[2] = {-1e30f, -1e30f};
  float li[2] = {0.f, 0.f};

  const int kRow = lane >> 3, kCh = (lane & 7) ^ ((lane >> 3) & 7);
  const int vRow = lane >> 4;
  auto stageK = [&](int kt, int buf) {
    #pragma unroll
    for (int s = 0; s < 2; ++s) {
      const int R = wv * 16 + s * 8;
      async16(Kb + (size_t)(kt * 128 + R + kRow) * 64 + kCh * 8, &Ks[buf][R * 64]);
    }
  };
  auto stageV = [&](int kt) {
    #pragma unroll
    for (int s = 0; s < 2; ++s) {
      const int D = wv * 8 + s * 4;
      const int dd = D + vRow;
      const int sch = (lane & 15) ^ (dd & 15);
      async16(Vb + (size_t)dd * 2048 + kt * 128 + sch * 8, &Vs[D * 128]);
    }
  };

  // P-redistribution lane constants (register butterfly):
  // target quad q pulls j = 2c+(q>>1) from source quads {2(q&1), 2(q&1)+1}
  const int ps0 = l16 + 16 * (2 * (quad & 1) + (quad >> 1));
  const int ps1 = ps0 ^ 16;
  const bool qlo = (quad & 1) == 0;
  const bool qh2 = (quad >> 1) == 0;

  // QK^T for one tile (S^T layout), Ks re-read per tile to keep sa live range at 8
  auto qkt = [&](const u16* KsC, bf16x8* qv, f32x4* sa) {
    __builtin_amdgcn_s_setprio(1);
    #pragma unroll
    for (int j = 0; j < 8; ++j) {
      const int key7 = l16 & 7;
      bf16x8 kf0 = *(const bf16x8*)(KsC + (16 * j + l16) * 64 + ((quad ^ key7) * 8));
      bf16x8 kf1 = *(const bf16x8*)(KsC + (16 * j + l16) * 64 + (((4 + quad) ^ key7) * 8));
      sa[j] = MFMA16(kf1, qv[1], MFMA16(kf0, qv[0], fz));
    }
    __builtin_amdgcn_s_setprio(0);
  };

  // softmax + butterfly for one tile; sa consumed, pf produced
  auto smx = [&](f32x4* sa, int t, int kt, int qt, PFU* pf) {
    if (kt == qt) {
      const int rg = rb + l16;
      #pragma unroll
      for (int j = 0; j < 8; ++j)
        #pragma unroll
        for (int r = 0; r < 4; ++r)
          if (j * 16 + quad * 4 + r > rg) sa[j][r] = -1e30f;
    }
    // tree max
    float mj[8];
    #pragma unroll
    for (int j = 0; j < 8; ++j)
      mj[j] = fmaxf(fmaxf(sa[j][0], sa[j][1]), fmaxf(sa[j][2], sa[j][3]));
    float mx = fmaxf(fmaxf(fmaxf(mj[0], mj[1]), fmaxf(mj[2], mj[3])),
                     fmaxf(fmaxf(mj[4], mj[5]), fmaxf(mj[6], mj[7])));
    mx = fmaxf(mx, __shfl_xor(mx, 16));
    mx = fmaxf(mx, __shfl_xor(mx, 32));
    mx *= S2;
    // defer-max: keep old running max when bounded (exact; P <= 2^8)
    const bool skip = (__all(mx - mi[t] <= 8.f) != 0);
    float mn = mi[t];
    float al = 1.f;
    if (!skip) {
      mn = fmaxf(mi[t], mx);
      al = __builtin_amdgcn_exp2f(mi[t] - mn);
      mi[t] = mn;
    }
    float r0 = 0.f, r1 = 0.f, r2 = 0.f, r3 = 0.f;
    unsigned w01[8], w23[8];
    #pragma unroll
    for (int j = 0; j < 8; ++j) {
      const float p0 = __builtin_amdgcn_exp2f(sa[j][0] * S2 - mn);
      const float p1 = __builtin_amdgcn_exp2f(sa[j][1] * S2 - mn);
      const float p2 = __builtin_amdgcn_exp2f(sa[j][2] * S2 - mn);
      const float p3 = __builtin_amdgcn_exp2f(sa[j][3] * S2 - mn);
      r0 += p0; r1 += p1; r2 += p2; r3 += p3;
      w01[j] = (unsigned)f2bf(p0) | ((unsigned)f2bf(p1) << 16);
      w23[j] = (unsigned)f2bf(p2) | ((unsigned)f2bf(p3) << 16);
    }
    float rs = (r0 + r1) + (r2 + r3);
    rs += __shfl_xor(rs, 16);
    rs += __shfl_xor(rs, 32);
    if (skip) {
      li[t] += rs;
    } else {
      li[t] = li[t] * al + rs;
      #pragma unroll
      for (int r = 0; r < 4; ++r) {
        const float alr = __shfl(al, quad * 4 + r);
        #pragma unroll
        for (int jd = 0; jd < 4; ++jd) octx[t][jd][r] *= alr;
      }
    }
    // butterfly P -> PV A-fragments
    #pragma unroll
    for (int c = 0; c < 4; ++c) {
      const unsigned a0 = qlo ? w01[2 * c] : w01[2 * c + 1];
      const unsigned a1 = qlo ? w01[2 * c + 1] : w01[2 * c];
      const unsigned b0 = qlo ? w23[2 * c] : w23[2 * c + 1];
      const unsigned b1 = qlo ? w23[2 * c + 1] : w23[2 * c];
      const unsigned r00 = (unsigned)__shfl((int)a0, ps0);
      const unsigned r01 = (unsigned)__shfl((int)a1, ps1);
      const unsigned r10 = (unsigned)__shfl((int)b0, ps0);
      const unsigned r11 = (unsigned)__shfl((int)b1, ps1);
      pf[c].d[0] = qh2 ? r00 : r01;
      pf[c].d[2] = qh2 ? r01 : r00;
      pf[c].d[1] = qh2 ? r10 : r11;
      pf[c].d[3] = qh2 ? r11 : r10;
    }
  };

  auto pv = [&](PFU* pf, f32x4* oc) {
    __builtin_amdgcn_s_setprio(1);
    #pragma unroll
    for (int c = 0; c < 4; ++c) {
      #pragma unroll
      for (int jd = 0; jd < 4; ++jd) {
        const int dd = jd * 16 + l16;
        bf16x8 vf = *(const bf16x8*)(Vs + dd * 128 + (((c * 4 + quad) ^ (dd & 15)) * 8));
        oc[jd] = MFMA16(pf[c].v, vf, oc[jd]);
      }
    }
    __builtin_amdgcn_s_setprio(0);
  };

  stageK(0, 0);
  __builtin_amdgcn_s_waitcnt(0xF70);  // vmcnt(0)
  __syncthreads();

  for (int kt = 0; kt <= qt1; ++kt) {
    const int cur = kt & 1;
    stageV(kt);
    if (kt < qt1) stageK(kt + 1, cur ^ 1);
    const bool both = (kt <= qt0);
    const u16* KsC = Ks[cur];

    // sequential per-tile QK^T + softmax (one sa[8] live at a time);
    // both softmaxes overlap the in-flight V/K loads
    PFU pf0[4], pf1[4];
    {
      f32x4 sa[8];
      if (both) {
        qkt(KsC, qf[0], sa);
        smx(sa, 0, kt, qt0, pf0);
      }
      qkt(KsC, qf[1], sa);
      smx(sa, 1, kt, qt1, pf1);
    }

    __builtin_amdgcn_s_waitcnt(0xF70);  // vmcnt(0): Vs (and K prefetch) landed
    __syncthreads();

    if (both) pv(pf0, octx[0]);
    pv(pf1, octx[1]);
    __syncthreads();  // Vs consumed by all waves before next restage
  }

  // epilogue: /l, write [B][T][H*d] bf16
  #pragma unroll
  for (int t = 0; t < 2; ++t) {
    const int qt = t ? qt1 : qt0;
    #pragma unroll
    for (int r = 0; r < 4; ++r) {
      const float lr = __builtin_amdgcn_rcpf(__shfl(li[t], quad * 4 + r));
      const int rowg = qt * 128 + rb + quad * 4 + r;
      #pragma unroll
      for (int jd = 0; jd < 4; ++jd) {
        const int col = h * 64 + jd * 16 + l16;
        ctx[((size_t)b * 2048 + rowg) * 1024 + col] = f2bf(octx[t][jd][r] * lr);
      }
    }
  }
}

// ---------------- launch ----------------
extern "C" void kernel_launch(void* const* d_in, const int* in_sizes, int n_in,
                              void* d_out, int out_size, void* d_ws, size_t ws_size,
                              hipStream_t stream) {
  (void)in_sizes; (void)n_in; (void)out_size; (void)ws_size;
  const float* x      = (const float*)d_in[0];
  const float* ln1_w  = (const float*)d_in[1];
  const float* ln1_b  = (const float*)d_in[2];
  const float* w_qkv  = (const float*)d_in[3];
  const float* b_qkv  = (const float*)d_in[4];
  const float* w_attn = (const float*)d_in[5];
  const float* b_attn = (const float*)d_in[6];
  const float* ln2_w  = (const float*)d_in[7];
  const float* ln2_b  = (const float*)d_in[8];
  const float* w_fc   = (const float*)d_in[9];
  const float* b_fc   = (const float*)d_in[10];
  const float* w_proj = (const float*)d_in[11];
  const float* b_proj = (const float*)d_in[12];
  float* out = (float*)d_out;

  char* ws = (char*)d_ws;
  size_t off = 0;
  auto alloc = [&](size_t n) {
    char* p = ws + off;
    off += (n + 255) & ~(size_t)255;
    return p;
  };
  u16* h1     = (u16*)alloc(4096ull * 1024 * 2);
  u16* wqkvT  = (u16*)alloc(3072ull * 1024 * 2);
  u16* wattnT = (u16*)alloc(1024ull * 1024 * 2);
  u16* wfcT   = (u16*)alloc(4096ull * 1024 * 2);
  u16* wprojT = (u16*)alloc(1024ull * 4096 * 2);
  u16* q      = (u16*)alloc(4096ull * 1024 * 2);
  u16* k      = (u16*)alloc(4096ull * 1024 * 2);
  u16* vT     = (u16*)alloc(4096ull * 1024 * 2);
  u16* ctxb   = (u16*)alloc(4096ull * 1024 * 2);
  float* out1 = (float*)alloc(4096ull * 1024 * 4);
  u16* h2     = (u16*)alloc(4096ull * 1024 * 2);
  u16* fco    = (u16*)alloc(4096ull * 4096 * 2);

  u16* vtmp = ctxb;             // dead until attn; raw V [B,H,T,d]
  float* apP = (float*)fco;     // fco dead until FC: attn-proj split-K partials (32 MB)
  float* projP = (float*)q;     // q..ctxb (32 MB) dead after attn-proj: proj partials

  const dim3 tb(32, 8);
  transpose_bf16<<<dim3(3072 / 32, 1024 / 32), tb, 0, stream>>>(w_qkv, wqkvT, 1024, 3072);
  transpose_bf16<<<dim3(1024 / 32, 1024 / 32), tb, 0, stream>>>(w_attn, wattnT, 1024, 1024);
  transpose_bf16<<<dim3(4096 / 32, 1024 / 32), tb, 0, stream>>>(w_fc, wfcT, 1024, 4096);
  transpose_bf16<<<dim3(1024 / 32, 4096 / 32), tb, 0, stream>>>(w_proj, wprojT, 4096, 1024);

  ln_bf16<<<4096, 256, 0, stream>>>(x, ln1_w, ln1_b, h1);

  gemm256<0><<<dim3(192), 512, 0, stream>>>(h1, wqkvT, b_qkv, nullptr, q, k, vtmp,
                                            4096, 3072, 1024);

  transpose_v<<<dim3(32, 32), 256, 0, stream>>>(vtmp, vT);

  attn<<<dim3(8, 32), 512, 0, stream>>>(q, k, vT, ctxb);

  gemm_bt<4><<<dim3(8, 32, 2), 256, 0, stream>>>(ctxb, wattnT, b_attn, nullptr, apP, nullptr,
                                                 nullptr, nullptr, nullptr, 4096, 1024, 1024, 512);
  reduce2_ln<<<4096, 256, 0, stream>>>(apP, x, b_attn, ln2_w, ln2_b, out1, h2, 4096 * 1024);

  gemm256<2><<<dim3(256), 512, 0, stream>>>(h2, wfcT, b_fc, fco, nullptr, nullptr, nullptr,
                                            4096, 4096, 1024);

  gemm_bt<4><<<dim3(8, 32, 2), 256, 0, stream>>>(fco, wprojT, b_proj, nullptr, projP, nullptr,
                                                 nullptr, nullptr, nullptr, 4096, 1024, 4096, 2048);

  reduce2<<<4096, 256, 0, stream>>>(projP, out1, b_proj, out, 4096 * 1024, 1024);
}

// Round 7
// 354.187 us; speedup vs baseline: 1.0260x; 1.0260x over previous
//
#include <hip/hip_runtime.h>

typedef unsigned short u16;
typedef __attribute__((ext_vector_type(8))) __bf16 bf16x8;
typedef __attribute__((ext_vector_type(8))) unsigned short ushort8;
typedef __attribute__((ext_vector_type(4))) float f32x4;

#define MFMA16(a, b, c) __builtin_amdgcn_mfma_f32_16x16x32_bf16((a), (b), (c), 0, 0, 0)

__device__ __forceinline__ u16 f2bf(float f) {
  union { __bf16 h; u16 u; } cv;
  cv.h = (__bf16)f;
  return cv.u;
}

__device__ __forceinline__ void async16(const u16* g, u16* l) {
  __builtin_amdgcn_global_load_lds(
      (const __attribute__((address_space(1))) void*)g,
      (__attribute__((address_space(3))) void*)l, 16, 0, 0);
}

// ---------------- weight transpose fp32 [K][N] -> bf16 [N][K] ----------------
__global__ __launch_bounds__(256)
void transpose_bf16(const float* __restrict__ W, u16* __restrict__ Wt, int K, int N) {
  __shared__ float t[32][33];
  const int n0 = blockIdx.x * 32, k0 = blockIdx.y * 32;
  const int tx = threadIdx.x, ty = threadIdx.y;
  #pragma unroll
  for (int i = 0; i < 32; i += 8)
    t[ty + i][tx] = W[(size_t)(k0 + ty + i) * N + n0 + tx];
  __syncthreads();
  #pragma unroll
  for (int i = 0; i < 32; i += 8)
    Wt[(size_t)(n0 + ty + i) * K + k0 + tx] = f2bf(t[tx][ty + i]);
}

// ---------------- bf16 transpose for V: [B*H][2048][64] -> [B*H][64][2048] ----------------
__global__ __launch_bounds__(256)
void transpose_v(const u16* __restrict__ v, u16* __restrict__ vt) {
  __shared__ u16 t[64][72];
  const int bh = blockIdx.y, t0 = blockIdx.x * 64;
  const int tid = threadIdx.x;
  #pragma unroll
  for (int s = 0; s < 2; ++s) {
    const int idx = tid + s * 256;
    const int row = idx >> 3, ch = idx & 7;
    ushort8 d = *(const ushort8*)(v + ((size_t)bh * 2048 + t0 + row) * 64 + ch * 8);
    #pragma unroll
    for (int e = 0; e < 8; ++e) t[ch * 8 + e][row] = d[e];
  }
  __syncthreads();
  #pragma unroll
  for (int s = 0; s < 2; ++s) {
    const int idx = tid + s * 256;
    const int drow = idx >> 3, ch = idx & 7;
    ushort8 o = *(const ushort8*)(&t[drow][ch * 8]);
    *(ushort8*)(vt + ((size_t)bh * 64 + drow) * 2048 + t0 + ch * 8) = o;
  }
}

// ---------------- layernorm fp32 [4096][1024] -> bf16 ----------------
__global__ __launch_bounds__(256)
void ln_bf16(const float* __restrict__ X, const float* __restrict__ w,
             const float* __restrict__ bia, u16* __restrict__ out) {
  const int row = blockIdx.x, tid = threadIdx.x;
  const float4 v = ((const float4*)(X + (size_t)row * 1024))[tid];
  float s = v.x + v.y + v.z + v.w;
  float s2 = v.x * v.x + v.y * v.y + v.z * v.z + v.w * v.w;
  #pragma unroll
  for (int o = 32; o > 0; o >>= 1) { s += __shfl_down(s, o); s2 += __shfl_down(s2, o); }
  __shared__ float red[8];
  const int wv = tid >> 6, lane = tid & 63;
  if (lane == 0) { red[wv] = s; red[4 + wv] = s2; }
  __syncthreads();
  s = red[0] + red[1] + red[2] + red[3];
  s2 = red[4] + red[5] + red[6] + red[7];
  const float mean = s * (1.f / 1024.f);
  const float var = s2 * (1.f / 1024.f) - mean * mean;
  const float rstd = rsqrtf(var + 1e-5f);
  const float4 wv4 = ((const float4*)w)[tid];
  const float4 bv4 = ((const float4*)bia)[tid];
  ushort4 o;
  o.x = f2bf((v.x - mean) * rstd * wv4.x + bv4.x);
  o.y = f2bf((v.y - mean) * rstd * wv4.y + bv4.y);
  o.z = f2bf((v.z - mean) * rstd * wv4.z + bv4.z);
  o.w = f2bf((v.w - mean) * rstd * wv4.w + bv4.w);
  ((ushort4*)(out + (size_t)row * 1024))[tid] = o;
}

// ---------------- 128-tile GEMM (split-K partials): C = A * Bt^T ----------------
template <int MODE>
__global__ __launch_bounds__(256)
void gemm_bt(const u16* __restrict__ A, const u16* __restrict__ Bt,
             const float* __restrict__ bias, const float* __restrict__ resid,
             float* __restrict__ outF, u16* __restrict__ outB,
             u16* __restrict__ qo, u16* __restrict__ ko, u16* __restrict__ vo,
             int M, int N, int K, int kSlice) {
  __shared__ u16 As[128 * 64];
  __shared__ u16 Bs[128 * 64];
  const int tid = threadIdx.x;
  const int lane = tid & 63, wv = tid >> 6;
  const int l16 = lane & 15, quad = lane >> 4;
  const int wr = wv >> 1, wc = wv & 1;
  const int m0 = blockIdx.y * 128, n0 = blockIdx.x * 128;
  const int kBegin = blockIdx.z * kSlice, kEnd = kBegin + kSlice;
  const int srow = lane >> 3;
  const int sch = (lane & 7) ^ srow;

  f32x4 acc[4][4];
  const f32x4 fz = {0.f, 0.f, 0.f, 0.f};
  #pragma unroll
  for (int i = 0; i < 4; ++i)
    #pragma unroll
    for (int j = 0; j < 4; ++j) acc[i][j] = fz;

  for (int k0 = kBegin; k0 < kEnd; k0 += 64) {
    __syncthreads();
    #pragma unroll
    for (int s = 0; s < 4; ++s) {
      const int R = wv * 32 + s * 8;
      async16(A + (size_t)(m0 + R + srow) * K + k0 + sch * 8, As + R * 64);
      async16(Bt + (size_t)(n0 + R + srow) * K + k0 + sch * 8, Bs + R * 64);
    }
    __builtin_amdgcn_s_waitcnt(0xF70);  // vmcnt(0)
    __syncthreads();
    #pragma unroll
    for (int h = 0; h < 2; ++h) {
      bf16x8 af[4], bfr[4];
      #pragma unroll
      for (int i = 0; i < 4; ++i) {
        const int row = wr * 64 + i * 16 + l16;
        af[i] = *(const bf16x8*)(As + row * 64 + (((h * 4 + quad) ^ (l16 & 7)) * 8));
      }
      #pragma unroll
      for (int j = 0; j < 4; ++j) {
        const int row = wc * 64 + j * 16 + l16;
        bfr[j] = *(const bf16x8*)(Bs + row * 64 + (((h * 4 + quad) ^ (l16 & 7)) * 8));
      }
      #pragma unroll
      for (int i = 0; i < 4; ++i)
        #pragma unroll
        for (int j = 0; j < 4; ++j)
          acc[i][j] = MFMA16(af[i], bfr[j], acc[i][j]);
    }
  }

  #pragma unroll
  for (int i = 0; i < 4; ++i) {
    #pragma unroll
    for (int j = 0; j < 4; ++j) {
      const int col = n0 + wc * 64 + j * 16 + l16;
      #pragma unroll
      for (int r = 0; r < 4; ++r) {
        const int row = m0 + wr * 64 + i * 16 + quad * 4 + r;
        outF[(size_t)blockIdx.z * M * N + (size_t)row * N + col] = acc[i][j][r];
      }
    }
  }
}

// ---------------- 256x256 GEMM, 8-phase counted pipeline (m201 port) ----------------
// BK=64, 8 waves (2Mx4N), LDS 2dbuf x [256][64] per operand (128 KiB). Iteration j
// consumes tiles ta=2j (dbuf0, phases 0-3) and tb=2j+1 (dbuf1, phases 4-7). Each phase:
//   {stage <=1 half-tile || ds_read frags} -> s_barrier -> lgkmcnt(0)+sched_barrier ->
//   setprio(1) 16 MFMA setprio(0) -> [vmcnt(4) at ph3/ph7 only] -> s_barrier.
// Stage ledger (WAR: issue only after the closing barrier where the buffer's previous
// occupant was last read; B dies at ph0/ph4 close, A at ph3/ph7 close):
//   ph0: A(tb,h0)      ph1: A(tb,h1), B(ta+2,h0)   ph2: B(ta+2,h1)   ph3: vmcnt(4)
//   ph4: A(ta+2,h0)    ph5: A(ta+2,h1)             ph6: B(tb+2,h0)
//   ph7: B(tb+2,h1), vmcnt(4)
// RAW: vmcnt(4) (2 loads/half-tile) leaves exactly the 2 newest half-tiles in flight
// across the barrier — never drains mid-loop (T4). Issue order in ph1: A before B.
// B-frags read once per K-tile (ph0/ph4), held in regs; A-frags 4xb128 per phase.
// Same XOR-8 chunk swizzle + linear-LDS-dest/pre-swizzled-source staging as before
// (bank-conflict counter was 0). Plain launch_bounds(512) — (512,2) spills (r4).
// MODE 0: qkv scatter (+bias).  MODE 2: outB = gelu(acc+bias) bf16.
template <int MODE>
__global__ __launch_bounds__(512)
void gemm256(const u16* __restrict__ A, const u16* __restrict__ Bt,
             const float* __restrict__ bias, u16* __restrict__ outB,
             u16* __restrict__ qo, u16* __restrict__ ko, u16* __restrict__ vo,
             int M, int N, int K) {
  __shared__ u16 Al[2][256 * 64];
  __shared__ u16 Bl[2][256 * 64];
  const int tid = threadIdx.x;
  const int lane = tid & 63, wv = tid >> 6;  // 8 waves
  const int l16 = lane & 15, quad = lane >> 4;
  const int wm = wv >> 2, wn = wv & 3;       // 2x4 wave grid, 128x64 out/wave
  // XCD-aware bijective swizzle (grid % 8 == 0)
  const int nwg = gridDim.x, cpx = nwg >> 3;
  const int bid = (int)blockIdx.x;
  const int swz = (bid & 7) * cpx + (bid >> 3);
  const int nbx = N >> 8;
  const int m0 = (swz / nbx) * 256, n0 = (swz % nbx) * 256;
  const int stR = lane >> 3, stC = lane & 7;
  const int stSrc = stC ^ stR;  // source chunk for linear-dest swizzled staging

  f32x4 acc[8][4];
  const f32x4 fz = {0.f, 0.f, 0.f, 0.f};
  #pragma unroll
  for (int i = 0; i < 8; ++i)
    #pragma unroll
    for (int j = 0; j < 4; ++j) acc[i][j] = fz;

  // stage one 128-row half-tile (2 loads/thread): rows rowBase+h*128 .. +127
  auto stageH = [&](const u16* G, int rowBase, u16* L, int kt, int h) {
    #pragma unroll
    for (int s = 0; s < 2; ++s) {
      const int r = wv * 8 + stR + s * 64;  // 0..127, r%8 == stR
      async16(G + (size_t)(rowBase + h * 128 + r) * K + kt * 64 + stSrc * 8,
              L + (h * 128 + r) * 64);
    }
  };
  auto ldf = [&](const u16* base, int row, int sel) {
    return *(const bf16x8*)(base + row * 64 + ((sel ^ (row & 7)) * 8));
  };

  bf16x8 bfr[4][2];  // B-frags for the current K-tile, persistent across 4 phases
  auto phase = [&](const u16* Ab, const u16* Bb, int q, bool loadB, bool vm4) {
    if (loadB) {
      #pragma unroll
      for (int j4 = 0; j4 < 4; ++j4)
        #pragma unroll
        for (int h = 0; h < 2; ++h)
          bfr[j4][h] = ldf(Bb, wn * 64 + j4 * 16 + l16, h * 4 + quad);
    }
    bf16x8 a[2][2];
    #pragma unroll
    for (int rt = 0; rt < 2; ++rt)
      #pragma unroll
      for (int h = 0; h < 2; ++h)
        a[rt][h] = ldf(Ab, wm * 128 + q * 32 + rt * 16 + l16, h * 4 + quad);
    __builtin_amdgcn_s_barrier();
    __builtin_amdgcn_s_waitcnt(0xC07F);  // lgkmcnt(0) only
    __builtin_amdgcn_sched_barrier(0);
    __builtin_amdgcn_s_setprio(1);
    #pragma unroll
    for (int rt = 0; rt < 2; ++rt)
      #pragma unroll
      for (int j4 = 0; j4 < 4; ++j4)
        #pragma unroll
        for (int h = 0; h < 2; ++h)
          acc[2 * q + rt][j4] = MFMA16(a[rt][h], bfr[j4][h], acc[2 * q + rt][j4]);
    __builtin_amdgcn_s_setprio(0);
    if (vm4) __builtin_amdgcn_s_waitcnt(0xF74);  // vmcnt(4): 2 newest half-tiles stay in flight
    __builtin_amdgcn_s_barrier();
    __builtin_amdgcn_sched_barrier(0);
  };

  const int nt = K >> 6;
  // prologue: tile 0 full + B(1); A(1) is staged in-loop at j=0 ph0/ph1 (steady state)
  stageH(A, m0, Al[0], 0, 0);
  stageH(A, m0, Al[0], 0, 1);
  stageH(Bt, n0, Bl[0], 0, 0);
  stageH(Bt, n0, Bl[0], 0, 1);
  stageH(Bt, n0, Bl[1], 1, 0);
  stageH(Bt, n0, Bl[1], 1, 1);
  __builtin_amdgcn_s_waitcnt(0xF70);  // vmcnt(0) (prologue only)
  __syncthreads();

  for (int j = 0; j < (nt >> 1); ++j) {
    const int ta = 2 * j, tb = 2 * j + 1;
    // ph0
    stageH(A, m0, Al[1], tb, 0);
    phase(Al[0], Bl[0], 0, true, false);
    // ph1 (issue order: A before B — vmcnt ledger)
    stageH(A, m0, Al[1], tb, 1);
    if (ta + 2 < nt) stageH(Bt, n0, Bl[0], ta + 2, 0);
    phase(Al[0], Bl[0], 1, false, false);
    // ph2
    if (ta + 2 < nt) stageH(Bt, n0, Bl[0], ta + 2, 1);
    phase(Al[0], Bl[0], 2, false, false);
    // ph3
    phase(Al[0], Bl[0], 3, false, true);
    // ph4
    if (ta + 2 < nt) stageH(A, m0, Al[0], ta + 2, 0);
    phase(Al[1], Bl[1], 0, true, false);
    // ph5
    if (ta + 2 < nt) stageH(A, m0, Al[0], ta + 2, 1);
    phase(Al[1], Bl[1], 1, false, false);
    // ph6
    if (tb + 2 < nt) stageH(Bt, n0, Bl[1], tb + 2, 0);
    phase(Al[1], Bl[1], 2, false, false);
    // ph7
    if (tb + 2 < nt) stageH(Bt, n0, Bl[1], tb + 2, 1);
    phase(Al[1], Bl[1], 3, false, true);
  }

  // ---- epilogue
  #pragma unroll
  for (int i = 0; i < 8; ++i) {
    #pragma unroll
    for (int j = 0; j < 4; ++j) {
      const int col = n0 + wn * 64 + j * 16 + l16;
      const float bc = bias[col];
      #pragma unroll
      for (int r = 0; r < 4; ++r) {
        const int row = m0 + wm * 128 + i * 16 + quad * 4 + r;
        float v = acc[i][j][r] + bc;
        if (MODE == 0) {
          const int which = col >> 10, cc = col & 1023, hh = cc >> 6, dd = cc & 63;
          const int bb = row >> 11, t = row & 2047;
          const u16 bv = f2bf(v);
          const size_t o = ((size_t)(bb * 16 + hh) * 2048 + t) * 64 + dd;
          if (which == 0)
            qo[o] = bv;
          else if (which == 1)
            ko[o] = bv;
          else
            vo[o] = bv;
        } else {
          const float x3 = v * v * v;
          const float u = 0.7978845608028654f * (v + 0.044715f * x3);
          const float e = __expf(2.f * u);
          const float th = 1.f - 2.f / (e + 1.f);
          outB[(size_t)row * N + col] = f2bf(0.5f * v * (1.f + th));
        }
      }
    }
  }
}

// ---------------- split-K reduce: out = resid + bias + P0 + P1 ----------------
__global__ __launch_bounds__(256)
void reduce2(const float* __restrict__ P, const float* __restrict__ resid,
             const float* __restrict__ bias, float* __restrict__ out, int MN, int N) {
  const int idx4 = blockIdx.x * 256 + threadIdx.x;
  const size_t s = (size_t)MN >> 2;
  const float4 a = ((const float4*)P)[idx4];
  const float4 b = ((const float4*)P)[idx4 + s];
  const float4 r = ((const float4*)resid)[idx4];
  const float4 bb = ((const float4*)bias)[idx4 & (N / 4 - 1)];
  float4 o;
  o.x = r.x + a.x + b.x + bb.x;
  o.y = r.y + a.y + b.y + bb.y;
  o.z = r.z + a.z + b.z + bb.z;
  o.w = r.w + a.w + b.w + bb.w;
  ((float4*)out)[idx4] = o;
}

// ---------------- fused split-K reduce + layernorm ----------------
__global__ __launch_bounds__(256)
void reduce2_ln(const float* __restrict__ P, const float* __restrict__ resid,
                const float* __restrict__ bias, const float* __restrict__ lw,
                const float* __restrict__ lb, float* __restrict__ out,
                u16* __restrict__ h2, int MN) {
  const int row = blockIdx.x, tid = threadIdx.x;
  const int idx4 = row * 256 + tid;
  const size_t s4 = (size_t)MN >> 2;
  const float4 a = ((const float4*)P)[idx4];
  const float4 b = ((const float4*)P)[idx4 + s4];
  const float4 r = ((const float4*)resid)[idx4];
  const float4 bb = ((const float4*)bias)[tid];
  float4 o;
  o.x = r.x + a.x + b.x + bb.x;
  o.y = r.y + a.y + b.y + bb.y;
  o.z = r.z + a.z + b.z + bb.z;
  o.w = r.w + a.w + b.w + bb.w;
  ((float4*)out)[idx4] = o;
  float s = o.x + o.y + o.z + o.w;
  float s2 = o.x * o.x + o.y * o.y + o.z * o.z + o.w * o.w;
  #pragma unroll
  for (int of = 32; of > 0; of >>= 1) { s += __shfl_down(s, of); s2 += __shfl_down(s2, of); }
  __shared__ float red[8];
  const int wv = tid >> 6, lane = tid & 63;
  if (lane == 0) { red[wv] = s; red[4 + wv] = s2; }
  __syncthreads();
  s = red[0] + red[1] + red[2] + red[3];
  s2 = red[4] + red[5] + red[6] + red[7];
  const float mean = s * (1.f / 1024.f);
  const float var = s2 * (1.f / 1024.f) - mean * mean;
  const float rstd = rsqrtf(var + 1e-5f);
  const float4 wv4 = ((const float4*)lw)[tid];
  const float4 bv4 = ((const float4*)lb)[tid];
  ushort4 ob;
  ob.x = f2bf((o.x - mean) * rstd * wv4.x + bv4.x);
  ob.y = f2bf((o.y - mean) * rstd * wv4.y + bv4.y);
  ob.z = f2bf((o.z - mean) * rstd * wv4.z + bv4.z);
  ob.w = f2bf((o.w - mean) * rstd * wv4.w + bv4.w);
  ((ushort4*)(h2 + (size_t)row * 1024))[tid] = ob;
}

// ---------------- flash attention (causal), S^T softmax, register-P, 8-wave merged ----------------
// (round-5 proven version)
typedef union { bf16x8 v; unsigned d[4]; } PFU;

__global__ __launch_bounds__(512)
void attn(const u16* __restrict__ Q, const u16* __restrict__ Kg,
          const u16* __restrict__ Vt, u16* __restrict__ ctx) {
  __shared__ u16 Ks[2][128 * 64];  // [key][64], chunk slot s holds global chunk s^(key&7)
  __shared__ u16 Vs[64 * 128];     // [d][128], chunk slot s holds global chunk s^(d&15)
  const int pair = blockIdx.x;     // 0..7
  const int qt0 = pair, qt1 = 15 - pair;
  const int bh = blockIdx.y;
  const int b = bh >> 4, h = bh & 15;
  const int tid = threadIdx.x;
  const int lane = tid & 63, wv = tid >> 6;  // 8 waves
  const int l16 = lane & 15, quad = lane >> 4;
  const int rb = wv * 16;                    // rows rb..rb+15 of each tile
  const float S2 = 0.18033688011112042f;     // 0.125 * log2(e)
  const u16* Qb = Q + (size_t)bh * 2048 * 64;
  const u16* Kb = Kg + (size_t)bh * 2048 * 64;
  const u16* Vb = Vt + (size_t)bh * 64 * 2048;

  bf16x8 qf[2][2];
  #pragma unroll
  for (int t = 0; t < 2; ++t)
    #pragma unroll
    for (int c = 0; c < 2; ++c)
      qf[t][c] = *(const bf16x8*)(Qb + (size_t)((t ? qt1 : qt0) * 128 + rb + l16) * 64 +
                                  c * 32 + quad * 8);

  f32x4 octx[2][4];
  const f32x4 fz = {0.f, 0.f, 0.f, 0.f};
  #pragma unroll
  for (int t = 0; t < 2; ++t)
    #pragma unroll
    for (int jd = 0; jd < 4; ++jd) octx[t][jd] = fz;
  float mi[2] = {-1e30f, -1e30f};
  float li[2] = {0.f, 0.f};

  const int kRow = lane >> 3, kCh = (lane & 7) ^ ((lane >> 3) & 7);
  const int vRow = lane >> 4;
  auto stageK = [&](int kt, int buf) {
    #pragma unroll
    for (int s = 0; s < 2; ++s) {
      const int R = wv * 16 + s * 8;
      async16(Kb + (size_t)(kt * 128 + R + kRow) * 64 + kCh * 8, &Ks[buf][R * 64]);
    }
  };
  auto stageV = [&](int kt) {
    #pragma unroll
    for (int s = 0; s < 2; ++s) {
      const int D = wv * 8 + s * 4;
      const int dd = D + vRow;
      const int sch = (lane & 15) ^ (dd & 15);
      async16(Vb + (size_t)dd * 2048 + kt * 128 + sch * 8, &Vs[D * 128]);
    }
  };

  // P-redistribution lane constants (register butterfly):
  // target quad q pulls j = 2c+(q>>1) from source quads {2(q&1), 2(q&1)+1}
  const int ps0 = l16 + 16 * (2 * (quad & 1) + (quad >> 1));
  const int ps1 = ps0 ^ 16;
  const bool qlo = (quad & 1) == 0;
  const bool qh2 = (quad >> 1) == 0;

  // QK^T for one tile (S^T layout), Ks re-read per tile to keep sa live range at 8
  auto qkt = [&](const u16* KsC, bf16x8* qv, f32x4* sa) {
    __builtin_amdgcn_s_setprio(1);
    #pragma unroll
    for (int j = 0; j < 8; ++j) {
      const int key7 = l16 & 7;
      bf16x8 kf0 = *(const bf16x8*)(KsC + (16 * j + l16) * 64 + ((quad ^ key7) * 8));
      bf16x8 kf1 = *(const bf16x8*)(KsC + (16 * j + l16) * 64 + (((4 + quad) ^ key7) * 8));
      sa[j] = MFMA16(kf1, qv[1], MFMA16(kf0, qv[0], fz));
    }
    __builtin_amdgcn_s_setprio(0);
  };

  // softmax + butterfly for one tile; sa consumed, pf produced
  auto smx = [&](f32x4* sa, int t, int kt, int qt, PFU* pf) {
    if (kt == qt) {
      const int rg = rb + l16;
      #pragma unroll
      for (int j = 0; j < 8; ++j)
        #pragma unroll
        for (int r = 0; r < 4; ++r)
          if (j * 16 + quad * 4 + r > rg) sa[j][r] = -1e30f;
    }
    // tree max
    float mj[8];
    #pragma unroll
    for (int j = 0; j < 8; ++j)
      mj[j] = fmaxf(fmaxf(sa[j][0], sa[j][1]), fmaxf(sa[j][2], sa[j][3]));
    float mx = fmaxf(fmaxf(fmaxf(mj[0], mj[1]), fmaxf(mj[2], mj[3])),
                     fmaxf(fmaxf(mj[4], mj[5]), fmaxf(mj[6], mj[7])));
    mx = fmaxf(mx, __shfl_xor(mx, 16));
    mx = fmaxf(mx, __shfl_xor(mx, 32));
    mx *= S2;
    // defer-max: keep old running max when bounded (exact; P <= 2^8)
    const bool skip = (__all(mx - mi[t] <= 8.f) != 0);
    float mn = mi[t];
    float al = 1.f;
    if (!skip) {
      mn = fmaxf(mi[t], mx);
      al = __builtin_amdgcn_exp2f(mi[t] - mn);
      mi[t] = mn;
    }
    float r0 = 0.f, r1 = 0.f, r2 = 0.f, r3 = 0.f;
    unsigned w01[8], w23[8];
    #pragma unroll
    for (int j = 0; j < 8; ++j) {
      const float p0 = __builtin_amdgcn_exp2f(sa[j][0] * S2 - mn);
      const float p1 = __builtin_amdgcn_exp2f(sa[j][1] * S2 - mn);
      const float p2 = __builtin_amdgcn_exp2f(sa[j][2] * S2 - mn);
      const float p3 = __builtin_amdgcn_exp2f(sa[j][3] * S2 - mn);
      r0 += p0; r1 += p1; r2 += p2; r3 += p3;
      w01[j] = (unsigned)f2bf(p0) | ((unsigned)f2bf(p1) << 16);
      w23[j] = (unsigned)f2bf(p2) | ((unsigned)f2bf(p3) << 16);
    }
    float rs = (r0 + r1) + (r2 + r3);
    rs += __shfl_xor(rs, 16);
    rs += __shfl_xor(rs, 32);
    if (skip) {
      li[t] += rs;
    } else {
      li[t] = li[t] * al + rs;
      #pragma unroll
      for (int r = 0; r < 4; ++r) {
        const float alr = __shfl(al, quad * 4 + r);
        #pragma unroll
        for (int jd = 0; jd < 4; ++jd) octx[t][jd][r] *= alr;
      }
    }
    // butterfly P -> PV A-fragments
    #pragma unroll
    for (int c = 0; c < 4; ++c) {
      const unsigned a0 = qlo ? w01[2 * c] : w01[2 * c + 1];
      const unsigned a1 = qlo ? w01[2 * c + 1] : w01[2 * c];
      const unsigned b0 = qlo ? w23[2 * c] : w23[2 * c + 1];
      const unsigned b1 = qlo ? w23[2 * c + 1] : w23[2 * c];
      const unsigned r00 = (unsigned)__shfl((int)a0, ps0);
      const unsigned r01 = (unsigned)__shfl((int)a1, ps1);
      const unsigned r10 = (unsigned)__shfl((int)b0, ps0);
      const unsigned r11 = (unsigned)__shfl((int)b1, ps1);
      pf[c].d[0] = qh2 ? r00 : r01;
      pf[c].d[2] = qh2 ? r01 : r00;
      pf[c].d[1] = qh2 ? r10 : r11;
      pf[c].d[3] = qh2 ? r11 : r10;
    }
  };

  auto pv = [&](PFU* pf, f32x4* oc) {
    __builtin_amdgcn_s_setprio(1);
    #pragma unroll
    for (int c = 0; c < 4; ++c) {
      #pragma unroll
      for (int jd = 0; jd < 4; ++jd) {
        const int dd = jd * 16 + l16;
        bf16x8 vf = *(const bf16x8*)(Vs + dd * 128 + (((c * 4 + quad) ^ (dd & 15)) * 8));
        oc[jd] = MFMA16(pf[c].v, vf, oc[jd]);
      }
    }
    __builtin_amdgcn_s_setprio(0);
  };

  stageK(0, 0);
  __builtin_amdgcn_s_waitcnt(0xF70);  // vmcnt(0)
  __syncthreads();

  for (int kt = 0; kt <= qt1; ++kt) {
    const int cur = kt & 1;
    stageV(kt);
    if (kt < qt1) stageK(kt + 1, cur ^ 1);
    const bool both = (kt <= qt0);
    const u16* KsC = Ks[cur];

    // sequential per-tile QK^T + softmax (one sa[8] live at a time);
    // both softmaxes overlap the in-flight V/K loads
    PFU pf0[4], pf1[4];
    {
      f32x4 sa[8];
      if (both) {
        qkt(KsC, qf[0], sa);
        smx(sa, 0, kt, qt0, pf0);
      }
      qkt(KsC, qf[1], sa);
      smx(sa, 1, kt, qt1, pf1);
    }

    __builtin_amdgcn_s_waitcnt(0xF70);  // vmcnt(0): Vs (and K prefetch) landed
    __syncthreads();

    if (both) pv(pf0, octx[0]);
    pv(pf1, octx[1]);
    __syncthreads();  // Vs consumed by all waves before next restage
  }

  // epilogue: /l, write [B][T][H*d] bf16
  #pragma unroll
  for (int t = 0; t < 2; ++t) {
    const int qt = t ? qt1 : qt0;
    #pragma unroll
    for (int r = 0; r < 4; ++r) {
      const float lr = __builtin_amdgcn_rcpf(__shfl(li[t], quad * 4 + r));
      const int rowg = qt * 128 + rb + quad * 4 + r;
      #pragma unroll
      for (int jd = 0; jd < 4; ++jd) {
        const int col = h * 64 + jd * 16 + l16;
        ctx[((size_t)b * 2048 + rowg) * 1024 + col] = f2bf(octx[t][jd][r] * lr);
      }
    }
  }
}

// ---------------- launch ----------------
extern "C" void kernel_launch(void* const* d_in, const int* in_sizes, int n_in,
                              void* d_out, int out_size, void* d_ws, size_t ws_size,
                              hipStream_t stream) {
  (void)in_sizes; (void)n_in; (void)out_size; (void)ws_size;
  const float* x      = (const float*)d_in[0];
  const float* ln1_w  = (const float*)d_in[1];
  const float* ln1_b  = (const float*)d_in[2];
  const float* w_qkv  = (const float*)d_in[3];
  const float* b_qkv  = (const float*)d_in[4];
  const float* w_attn = (const float*)d_in[5];
  const float* b_attn = (const float*)d_in[6];
  const float* ln2_w  = (const float*)d_in[7];
  const float* ln2_b  = (const float*)d_in[8];
  const float* w_fc   = (const float*)d_in[9];
  const float* b_fc   = (const float*)d_in[10];
  const float* w_proj = (const float*)d_in[11];
  const float* b_proj = (const float*)d_in[12];
  float* out = (float*)d_out;

  char* ws = (char*)d_ws;
  size_t off = 0;
  auto alloc = [&](size_t n) {
    char* p = ws + off;
    off += (n + 255) & ~(size_t)255;
    return p;
  };
  u16* h1     = (u16*)alloc(4096ull * 1024 * 2);
  u16* wqkvT  = (u16*)alloc(3072ull * 1024 * 2);
  u16* wattnT = (u16*)alloc(1024ull * 1024 * 2);
  u16* wfcT   = (u16*)alloc(4096ull * 1024 * 2);
  u16* wprojT = (u16*)alloc(1024ull * 4096 * 2);
  u16* q      = (u16*)alloc(4096ull * 1024 * 2);
  u16* k      = (u16*)alloc(4096ull * 1024 * 2);
  u16* vT     = (u16*)alloc(4096ull * 1024 * 2);
  u16* ctxb   = (u16*)alloc(4096ull * 1024 * 2);
  float* out1 = (float*)alloc(4096ull * 1024 * 4);
  u16* h2     = (u16*)alloc(4096ull * 1024 * 2);
  u16* fco    = (u16*)alloc(4096ull * 4096 * 2);

  u16* vtmp = ctxb;             // dead until attn; raw V [B,H,T,d]
  float* apP = (float*)fco;     // fco dead until FC: attn-proj split-K partials (32 MB)
  float* projP = (float*)q;     // q..ctxb (32 MB) dead after attn-proj: proj partials

  const dim3 tb(32, 8);
  transpose_bf16<<<dim3(3072 / 32, 1024 / 32), tb, 0, stream>>>(w_qkv, wqkvT, 1024, 3072);
  transpose_bf16<<<dim3(1024 / 32, 1024 / 32), tb, 0, stream>>>(w_attn, wattnT, 1024, 1024);
  transpose_bf16<<<dim3(4096 / 32, 1024 / 32), tb, 0, stream>>>(w_fc, wfcT, 1024, 4096);
  transpose_bf16<<<dim3(1024 / 32, 4096 / 32), tb, 0, stream>>>(w_proj, wprojT, 4096, 1024);

  ln_bf16<<<4096, 256, 0, stream>>>(x, ln1_w, ln1_b, h1);

  gemm256<0><<<dim3(192), 512, 0, stream>>>(h1, wqkvT, b_qkv, nullptr, q, k, vtmp,
                                            4096, 3072, 1024);

  transpose_v<<<dim3(32, 32), 256, 0, stream>>>(vtmp, vT);

  attn<<<dim3(8, 32), 512, 0, stream>>>(q, k, vT, ctxb);

  gemm_bt<4><<<dim3(8, 32, 2), 256, 0, stream>>>(ctxb, wattnT, b_attn, nullptr, apP, nullptr,
                                                 nullptr, nullptr, nullptr, 4096, 1024, 1024, 512);
  reduce2_ln<<<4096, 256, 0, stream>>>(apP, x, b_attn, ln2_w, ln2_b, out1, h2, 4096 * 1024);

  gemm256<2><<<dim3(256), 512, 0, stream>>>(h2, wfcT, b_fc, fco, nullptr, nullptr, nullptr,
                                            4096, 4096, 1024);

  gemm_bt<4><<<dim3(8, 32, 2), 256, 0, stream>>>(fco, wprojT, b_proj, nullptr, projP, nullptr,
                                                 nullptr, nullptr, nullptr, 4096, 1024, 4096, 2048);

  reduce2<<<4096, 256, 0, stream>>>(projP, out1, b_proj, out, 4096 * 1024, 1024);
}

// Round 8
// 340.511 us; speedup vs baseline: 1.0672x; 1.0402x over previous
//
#include <hip/hip_runtime.h>

typedef unsigned short u16;
typedef __attribute__((ext_vector_type(8))) __bf16 bf16x8;
typedef __attribute__((ext_vector_type(8))) unsigned short ushort8;
typedef __attribute__((ext_vector_type(4))) float f32x4;

#define MFMA16(a, b, c) __builtin_amdgcn_mfma_f32_16x16x32_bf16((a), (b), (c), 0, 0, 0)

__device__ __forceinline__ u16 f2bf(float f) {
  union { __bf16 h; u16 u; } cv;
  cv.h = (__bf16)f;
  return cv.u;
}

__device__ __forceinline__ void async16(const u16* g, u16* l) {
  __builtin_amdgcn_global_load_lds(
      (const __attribute__((address_space(1))) void*)g,
      (__attribute__((address_space(3))) void*)l, 16, 0, 0);
}

// ---------------- prep: 4 weight transposes + ln1, one launch ----------------
// blocks [0,3072): w_qkv tiles; [3072,4096): w_attn; [4096,8192): w_fc;
// [8192,12288): w_proj; [12288,16384): layernorm rows of x -> h1.
// All five sub-tasks are independent (read-only in -> distinct out); merged to cut
// 4 kernel-launch gaps (r7 budget: ~100us of wall not in any dispatch, 13 launches).
__global__ __launch_bounds__(256)
void prep(const float* __restrict__ w_qkv, const float* __restrict__ w_attn,
          const float* __restrict__ w_fc, const float* __restrict__ w_proj,
          const float* __restrict__ x, const float* __restrict__ lw,
          const float* __restrict__ lbias, u16* __restrict__ wqkvT,
          u16* __restrict__ wattnT, u16* __restrict__ wfcT,
          u16* __restrict__ wprojT, u16* __restrict__ h1) {
  __shared__ float sm[32 * 33];
  const int bid = blockIdx.x;
  const int tid = threadIdx.x;
  if (bid >= 12288) {
    // ---- layernorm row ----
    const int row = bid - 12288;
    const float4 v = ((const float4*)(x + (size_t)row * 1024))[tid];
    float s = v.x + v.y + v.z + v.w;
    float s2 = v.x * v.x + v.y * v.y + v.z * v.z + v.w * v.w;
    #pragma unroll
    for (int o = 32; o > 0; o >>= 1) { s += __shfl_down(s, o); s2 += __shfl_down(s2, o); }
    const int wv = tid >> 6, lane = tid & 63;
    if (lane == 0) { sm[wv] = s; sm[4 + wv] = s2; }
    __syncthreads();
    s = sm[0] + sm[1] + sm[2] + sm[3];
    s2 = sm[4] + sm[5] + sm[6] + sm[7];
    const float mean = s * (1.f / 1024.f);
    const float var = s2 * (1.f / 1024.f) - mean * mean;
    const float rstd = rsqrtf(var + 1e-5f);
    const float4 wv4 = ((const float4*)lw)[tid];
    const float4 bv4 = ((const float4*)lbias)[tid];
    ushort4 o;
    o.x = f2bf((v.x - mean) * rstd * wv4.x + bv4.x);
    o.y = f2bf((v.y - mean) * rstd * wv4.y + bv4.y);
    o.z = f2bf((v.z - mean) * rstd * wv4.z + bv4.z);
    o.w = f2bf((v.w - mean) * rstd * wv4.w + bv4.w);
    ((ushort4*)(h1 + (size_t)row * 1024))[tid] = o;
    return;
  }
  // ---- weight transpose fp32 [K][N] -> bf16 [N][K], 32x32 tile ----
  const float* W;
  u16* Wt;
  int K, N, nb, lb;
  if (bid < 3072) {
    W = w_qkv;  Wt = wqkvT;  K = 1024; N = 3072; nb = 96;  lb = bid;
  } else if (bid < 4096) {
    W = w_attn; Wt = wattnT; K = 1024; N = 1024; nb = 32;  lb = bid - 3072;
  } else if (bid < 8192) {
    W = w_fc;   Wt = wfcT;   K = 1024; N = 4096; nb = 128; lb = bid - 4096;
  } else {
    W = w_proj; Wt = wprojT; K = 4096; N = 1024; nb = 32;  lb = bid - 8192;
  }
  const int n0 = (lb % nb) * 32, k0 = (lb / nb) * 32;
  const int tx = tid & 31, ty = tid >> 5;
  float(*t)[33] = (float(*)[33])sm;
  #pragma unroll
  for (int i = 0; i < 32; i += 8)
    t[ty + i][tx] = W[(size_t)(k0 + ty + i) * N + n0 + tx];
  __syncthreads();
  #pragma unroll
  for (int i = 0; i < 32; i += 8)
    Wt[(size_t)(n0 + ty + i) * K + k0 + tx] = f2bf(t[tx][ty + i]);
}

// ---------------- bf16 transpose for V: [B*H][2048][64] -> [B*H][64][2048] ----------------
__global__ __launch_bounds__(256)
void transpose_v(const u16* __restrict__ v, u16* __restrict__ vt) {
  __shared__ u16 t[64][72];
  const int bh = blockIdx.y, t0 = blockIdx.x * 64;
  const int tid = threadIdx.x;
  #pragma unroll
  for (int s = 0; s < 2; ++s) {
    const int idx = tid + s * 256;
    const int row = idx >> 3, ch = idx & 7;
    ushort8 d = *(const ushort8*)(v + ((size_t)bh * 2048 + t0 + row) * 64 + ch * 8);
    #pragma unroll
    for (int e = 0; e < 8; ++e) t[ch * 8 + e][row] = d[e];
  }
  __syncthreads();
  #pragma unroll
  for (int s = 0; s < 2; ++s) {
    const int idx = tid + s * 256;
    const int drow = idx >> 3, ch = idx & 7;
    ushort8 o = *(const ushort8*)(&t[drow][ch * 8]);
    *(ushort8*)(vt + ((size_t)bh * 64 + drow) * 2048 + t0 + ch * 8) = o;
  }
}

// ---------------- 128-tile GEMM (split-K partials): C = A * Bt^T ----------------
template <int MODE>
__global__ __launch_bounds__(256)
void gemm_bt(const u16* __restrict__ A, const u16* __restrict__ Bt,
             const float* __restrict__ bias, const float* __restrict__ resid,
             float* __restrict__ outF, u16* __restrict__ outB,
             u16* __restrict__ qo, u16* __restrict__ ko, u16* __restrict__ vo,
             int M, int N, int K, int kSlice) {
  __shared__ u16 As[128 * 64];
  __shared__ u16 Bs[128 * 64];
  const int tid = threadIdx.x;
  const int lane = tid & 63, wv = tid >> 6;
  const int l16 = lane & 15, quad = lane >> 4;
  const int wr = wv >> 1, wc = wv & 1;
  const int m0 = blockIdx.y * 128, n0 = blockIdx.x * 128;
  const int kBegin = blockIdx.z * kSlice, kEnd = kBegin + kSlice;
  const int srow = lane >> 3;
  const int sch = (lane & 7) ^ srow;

  f32x4 acc[4][4];
  const f32x4 fz = {0.f, 0.f, 0.f, 0.f};
  #pragma unroll
  for (int i = 0; i < 4; ++i)
    #pragma unroll
    for (int j = 0; j < 4; ++j) acc[i][j] = fz;

  for (int k0 = kBegin; k0 < kEnd; k0 += 64) {
    __syncthreads();
    #pragma unroll
    for (int s = 0; s < 4; ++s) {
      const int R = wv * 32 + s * 8;
      async16(A + (size_t)(m0 + R + srow) * K + k0 + sch * 8, As + R * 64);
      async16(Bt + (size_t)(n0 + R + srow) * K + k0 + sch * 8, Bs + R * 64);
    }
    __builtin_amdgcn_s_waitcnt(0xF70);  // vmcnt(0)
    __syncthreads();
    #pragma unroll
    for (int h = 0; h < 2; ++h) {
      bf16x8 af[4], bfr[4];
      #pragma unroll
      for (int i = 0; i < 4; ++i) {
        const int row = wr * 64 + i * 16 + l16;
        af[i] = *(const bf16x8*)(As + row * 64 + (((h * 4 + quad) ^ (l16 & 7)) * 8));
      }
      #pragma unroll
      for (int j = 0; j < 4; ++j) {
        const int row = wc * 64 + j * 16 + l16;
        bfr[j] = *(const bf16x8*)(Bs + row * 64 + (((h * 4 + quad) ^ (l16 & 7)) * 8));
      }
      #pragma unroll
      for (int i = 0; i < 4; ++i)
        #pragma unroll
        for (int j = 0; j < 4; ++j)
          acc[i][j] = MFMA16(af[i], bfr[j], acc[i][j]);
    }
  }

  #pragma unroll
  for (int i = 0; i < 4; ++i) {
    #pragma unroll
    for (int j = 0; j < 4; ++j) {
      const int col = n0 + wc * 64 + j * 16 + l16;
      #pragma unroll
      for (int r = 0; r < 4; ++r) {
        const int row = m0 + wr * 64 + i * 16 + quad * 4 + r;
        outF[(size_t)blockIdx.z * M * N + (size_t)row * N + col] = acc[i][j][r];
      }
    }
  }
}

// ---------------- 256x256 GEMM, 8-phase counted pipeline (m201 port, r7 proven) ----------------
template <int MODE>
__global__ __launch_bounds__(512)
void gemm256(const u16* __restrict__ A, const u16* __restrict__ Bt,
             const float* __restrict__ bias, u16* __restrict__ outB,
             u16* __restrict__ qo, u16* __restrict__ ko, u16* __restrict__ vo,
             int M, int N, int K) {
  __shared__ u16 Al[2][256 * 64];
  __shared__ u16 Bl[2][256 * 64];
  const int tid = threadIdx.x;
  const int lane = tid & 63, wv = tid >> 6;  // 8 waves
  const int l16 = lane & 15, quad = lane >> 4;
  const int wm = wv >> 2, wn = wv & 3;       // 2x4 wave grid, 128x64 out/wave
  const int nwg = gridDim.x, cpx = nwg >> 3;
  const int bid = (int)blockIdx.x;
  const int swz = (bid & 7) * cpx + (bid >> 3);
  const int nbx = N >> 8;
  const int m0 = (swz / nbx) * 256, n0 = (swz % nbx) * 256;
  const int stR = lane >> 3, stC = lane & 7;
  const int stSrc = stC ^ stR;  // source chunk for linear-dest swizzled staging

  f32x4 acc[8][4];
  const f32x4 fz = {0.f, 0.f, 0.f, 0.f};
  #pragma unroll
  for (int i = 0; i < 8; ++i)
    #pragma unroll
    for (int j = 0; j < 4; ++j) acc[i][j] = fz;

  auto stageH = [&](const u16* G, int rowBase, u16* L, int kt, int h) {
    #pragma unroll
    for (int s = 0; s < 2; ++s) {
      const int r = wv * 8 + stR + s * 64;  // 0..127, r%8 == stR
      async16(G + (size_t)(rowBase + h * 128 + r) * K + kt * 64 + stSrc * 8,
              L + (h * 128 + r) * 64);
    }
  };
  auto ldf = [&](const u16* base, int row, int sel) {
    return *(const bf16x8*)(base + row * 64 + ((sel ^ (row & 7)) * 8));
  };

  bf16x8 bfr[4][2];  // B-frags for the current K-tile, persistent across 4 phases
  auto phase = [&](const u16* Ab, const u16* Bb, int q, bool loadB, bool vm4) {
    if (loadB) {
      #pragma unroll
      for (int j4 = 0; j4 < 4; ++j4)
        #pragma unroll
        for (int h = 0; h < 2; ++h)
          bfr[j4][h] = ldf(Bb, wn * 64 + j4 * 16 + l16, h * 4 + quad);
    }
    bf16x8 a[2][2];
    #pragma unroll
    for (int rt = 0; rt < 2; ++rt)
      #pragma unroll
      for (int h = 0; h < 2; ++h)
        a[rt][h] = ldf(Ab, wm * 128 + q * 32 + rt * 16 + l16, h * 4 + quad);
    __builtin_amdgcn_s_barrier();
    __builtin_amdgcn_s_waitcnt(0xC07F);  // lgkmcnt(0) only
    __builtin_amdgcn_sched_barrier(0);
    __builtin_amdgcn_s_setprio(1);
    #pragma unroll
    for (int rt = 0; rt < 2; ++rt)
      #pragma unroll
      for (int j4 = 0; j4 < 4; ++j4)
        #pragma unroll
        for (int h = 0; h < 2; ++h)
          acc[2 * q + rt][j4] = MFMA16(a[rt][h], bfr[j4][h], acc[2 * q + rt][j4]);
    __builtin_amdgcn_s_setprio(0);
    if (vm4) __builtin_amdgcn_s_waitcnt(0xF74);  // vmcnt(4)
    __builtin_amdgcn_s_barrier();
    __builtin_amdgcn_sched_barrier(0);
  };

  const int nt = K >> 6;
  stageH(A, m0, Al[0], 0, 0);
  stageH(A, m0, Al[0], 0, 1);
  stageH(Bt, n0, Bl[0], 0, 0);
  stageH(Bt, n0, Bl[0], 0, 1);
  stageH(Bt, n0, Bl[1], 1, 0);
  stageH(Bt, n0, Bl[1], 1, 1);
  __builtin_amdgcn_s_waitcnt(0xF70);  // vmcnt(0) (prologue only)
  __syncthreads();

  for (int j = 0; j < (nt >> 1); ++j) {
    const int ta = 2 * j, tb = 2 * j + 1;
    stageH(A, m0, Al[1], tb, 0);
    phase(Al[0], Bl[0], 0, true, false);
    stageH(A, m0, Al[1], tb, 1);
    if (ta + 2 < nt) stageH(Bt, n0, Bl[0], ta + 2, 0);
    phase(Al[0], Bl[0], 1, false, false);
    if (ta + 2 < nt) stageH(Bt, n0, Bl[0], ta + 2, 1);
    phase(Al[0], Bl[0], 2, false, false);
    phase(Al[0], Bl[0], 3, false, true);
    if (ta + 2 < nt) stageH(A, m0, Al[0], ta + 2, 0);
    phase(Al[1], Bl[1], 0, true, false);
    if (ta + 2 < nt) stageH(A, m0, Al[0], ta + 2, 1);
    phase(Al[1], Bl[1], 1, false, false);
    if (tb + 2 < nt) stageH(Bt, n0, Bl[1], tb + 2, 0);
    phase(Al[1], Bl[1], 2, false, false);
    if (tb + 2 < nt) stageH(Bt, n0, Bl[1], tb + 2, 1);
    phase(Al[1], Bl[1], 3, false, true);
  }

  #pragma unroll
  for (int i = 0; i < 8; ++i) {
    #pragma unroll
    for (int j = 0; j < 4; ++j) {
      const int col = n0 + wn * 64 + j * 16 + l16;
      const float bc = bias[col];
      #pragma unroll
      for (int r = 0; r < 4; ++r) {
        const int row = m0 + wm * 128 + i * 16 + quad * 4 + r;
        float v = acc[i][j][r] + bc;
        if (MODE == 0) {
          const int which = col >> 10, cc = col & 1023, hh = cc >> 6, dd = cc & 63;
          const int bb = row >> 11, t = row & 2047;
          const u16 bv = f2bf(v);
          const size_t o = ((size_t)(bb * 16 + hh) * 2048 + t) * 64 + dd;
          if (which == 0)
            qo[o] = bv;
          else if (which == 1)
            ko[o] = bv;
          else
            vo[o] = bv;
        } else {
          const float x3 = v * v * v;
          const float u = 0.7978845608028654f * (v + 0.044715f * x3);
          const float e = __expf(2.f * u);
          const float th = 1.f - 2.f / (e + 1.f);
          outB[(size_t)row * N + col] = f2bf(0.5f * v * (1.f + th));
        }
      }
    }
  }
}

// ---------------- split-K reduce: out = resid + bias + P0 + P1 ----------------
__global__ __launch_bounds__(256)
void reduce2(const float* __restrict__ P, const float* __restrict__ resid,
             const float* __restrict__ bias, float* __restrict__ out, int MN, int N) {
  const int idx4 = blockIdx.x * 256 + threadIdx.x;
  const size_t s = (size_t)MN >> 2;
  const float4 a = ((const float4*)P)[idx4];
  const float4 b = ((const float4*)P)[idx4 + s];
  const float4 r = ((const float4*)resid)[idx4];
  const float4 bb = ((const float4*)bias)[idx4 & (N / 4 - 1)];
  float4 o;
  o.x = r.x + a.x + b.x + bb.x;
  o.y = r.y + a.y + b.y + bb.y;
  o.z = r.z + a.z + b.z + bb.z;
  o.w = r.w + a.w + b.w + bb.w;
  ((float4*)out)[idx4] = o;
}

// ---------------- fused split-K reduce + layernorm ----------------
__global__ __launch_bounds__(256)
void reduce2_ln(const float* __restrict__ P, const float* __restrict__ resid,
                const float* __restrict__ bias, const float* __restrict__ lw,
                const float* __restrict__ lb, float* __restrict__ out,
                u16* __restrict__ h2, int MN) {
  const int row = blockIdx.x, tid = threadIdx.x;
  const int idx4 = row * 256 + tid;
  const size_t s4 = (size_t)MN >> 2;
  const float4 a = ((const float4*)P)[idx4];
  const float4 b = ((const float4*)P)[idx4 + s4];
  const float4 r = ((const float4*)resid)[idx4];
  const float4 bb = ((const float4*)bias)[tid];
  float4 o;
  o.x = r.x + a.x + b.x + bb.x;
  o.y = r.y + a.y + b.y + bb.y;
  o.z = r.z + a.z + b.z + bb.z;
  o.w = r.w + a.w + b.w + bb.w;
  ((float4*)out)[idx4] = o;
  float s = o.x + o.y + o.z + o.w;
  float s2 = o.x * o.x + o.y * o.y + o.z * o.z + o.w * o.w;
  #pragma unroll
  for (int of = 32; of > 0; of >>= 1) { s += __shfl_down(s, of); s2 += __shfl_down(s2, of); }
  __shared__ float red[8];
  const int wv = tid >> 6, lane = tid & 63;
  if (lane == 0) { red[wv] = s; red[4 + wv] = s2; }
  __syncthreads();
  s = red[0] + red[1] + red[2] + red[3];
  s2 = red[4] + red[5] + red[6] + red[7];
  const float mean = s * (1.f / 1024.f);
  const float var = s2 * (1.f / 1024.f) - mean * mean;
  const float rstd = rsqrtf(var + 1e-5f);
  const float4 wv4 = ((const float4*)lw)[tid];
  const float4 bv4 = ((const float4*)lb)[tid];
  ushort4 ob;
  ob.x = f2bf((o.x - mean) * rstd * wv4.x + bv4.x);
  ob.y = f2bf((o.y - mean) * rstd * wv4.y + bv4.y);
  ob.z = f2bf((o.z - mean) * rstd * wv4.z + bv4.z);
  ob.w = f2bf((o.w - mean) * rstd * wv4.w + bv4.w);
  ((ushort4*)(h2 + (size_t)row * 1024))[tid] = ob;
}

// ---------------- flash attention (causal), S^T softmax, register-P, 8-wave merged ----------------
// (round-5 proven version)
typedef union { bf16x8 v; unsigned d[4]; } PFU;

__global__ __launch_bounds__(512)
void attn(const u16* __restrict__ Q, const u16* __restrict__ Kg,
          const u16* __restrict__ Vt, u16* __restrict__ ctx) {
  __shared__ u16 Ks[2][128 * 64];  // [key][64], chunk slot s holds global chunk s^(key&7)
  __shared__ u16 Vs[64 * 128];     // [d][128], chunk slot s holds global chunk s^(d&15)
  const int pair = blockIdx.x;     // 0..7
  const int qt0 = pair, qt1 = 15 - pair;
  const int bh = blockIdx.y;
  const int b = bh >> 4, h = bh & 15;
  const int tid = threadIdx.x;
  const int lane = tid & 63, wv = tid >> 6;  // 8 waves
  const int l16 = lane & 15, quad = lane >> 4;
  const int rb = wv * 16;                    // rows rb..rb+15 of each tile
  const float S2 = 0.18033688011112042f;     // 0.125 * log2(e)
  const u16* Qb = Q + (size_t)bh * 2048 * 64;
  const u16* Kb = Kg + (size_t)bh * 2048 * 64;
  const u16* Vb = Vt + (size_t)bh * 64 * 2048;

  bf16x8 qf[2][2];
  #pragma unroll
  for (int t = 0; t < 2; ++t)
    #pragma unroll
    for (int c = 0; c < 2; ++c)
      qf[t][c] = *(const bf16x8*)(Qb + (size_t)((t ? qt1 : qt0) * 128 + rb + l16) * 64 +
                                  c * 32 + quad * 8);

  f32x4 octx[2][4];
  const f32x4 fz = {0.f, 0.f, 0.f, 0.f};
  #pragma unroll
  for (int t = 0; t < 2; ++t)
    #pragma unroll
    for (int jd = 0; jd < 4; ++jd) octx[t][jd] = fz;
  float mi[2] = {-1e30f, -1e30f};
  float li[2] = {0.f, 0.f};

  const int kRow = lane >> 3, kCh = (lane & 7) ^ ((lane >> 3) & 7);
  const int vRow = lane >> 4;
  auto stageK = [&](int kt, int buf) {
    #pragma unroll
    for (int s = 0; s < 2; ++s) {
      const int R = wv * 16 + s * 8;
      async16(Kb + (size_t)(kt * 128 + R + kRow) * 64 + kCh * 8, &Ks[buf][R * 64]);
    }
  };
  auto stageV = [&](int kt) {
    #pragma unroll
    for (int s = 0; s < 2; ++s) {
      const int D = wv * 8 + s * 4;
      const int dd = D + vRow;
      const int sch = (lane & 15) ^ (dd & 15);
      async16(Vb + (size_t)dd * 2048 + kt * 128 + sch * 8, &Vs[D * 128]);
    }
  };

  const int ps0 = l16 + 16 * (2 * (quad & 1) + (quad >> 1));
  const int ps1 = ps0 ^ 16;
  const bool qlo = (quad & 1) == 0;
  const bool qh2 = (quad >> 1) == 0;

  auto qkt = [&](const u16* KsC, bf16x8* qv, f32x4* sa) {
    __builtin_amdgcn_s_setprio(1);
    #pragma unroll
    for (int j = 0; j < 8; ++j) {
      const int key7 = l16 & 7;
      bf16x8 kf0 = *(const bf16x8*)(KsC + (16 * j + l16) * 64 + ((quad ^ key7) * 8));
      bf16x8 kf1 = *(const bf16x8*)(KsC + (16 * j + l16) * 64 + (((4 + quad) ^ key7) * 8));
      sa[j] = MFMA16(kf1, qv[1], MFMA16(kf0, qv[0], fz));
    }
    __builtin_amdgcn_s_setprio(0);
  };

  auto smx = [&](f32x4* sa, int t, int kt, int qt, PFU* pf) {
    if (kt == qt) {
      const int rg = rb + l16;
      #pragma unroll
      for (int j = 0; j < 8; ++j)
        #pragma unroll
        for (int r = 0; r < 4; ++r)
          if (j * 16 + quad * 4 + r > rg) sa[j][r] = -1e30f;
    }
    float mj[8];
    #pragma unroll
    for (int j = 0; j < 8; ++j)
      mj[j] = fmaxf(fmaxf(sa[j][0], sa[j][1]), fmaxf(sa[j][2], sa[j][3]));
    float mx = fmaxf(fmaxf(fmaxf(mj[0], mj[1]), fmaxf(mj[2], mj[3])),
                     fmaxf(fmaxf(mj[4], mj[5]), fmaxf(mj[6], mj[7])));
    mx = fmaxf(mx, __shfl_xor(mx, 16));
    mx = fmaxf(mx, __shfl_xor(mx, 32));
    mx *= S2;
    const bool skip = (__all(mx - mi[t] <= 8.f) != 0);
    float mn = mi[t];
    float al = 1.f;
    if (!skip) {
      mn = fmaxf(mi[t], mx);
      al = __builtin_amdgcn_exp2f(mi[t] - mn);
      mi[t] = mn;
    }
    float r0 = 0.f, r1 = 0.f, r2 = 0.f, r3 = 0.f;
    unsigned w01[8], w23[8];
    #pragma unroll
    for (int j = 0; j < 8; ++j) {
      const float p0 = __builtin_amdgcn_exp2f(sa[j][0] * S2 - mn);
      const float p1 = __builtin_amdgcn_exp2f(sa[j][1] * S2 - mn);
      const float p2 = __builtin_amdgcn_exp2f(sa[j][2] * S2 - mn);
      const float p3 = __builtin_amdgcn_exp2f(sa[j][3] * S2 - mn);
      r0 += p0; r1 += p1; r2 += p2; r3 += p3;
      w01[j] = (unsigned)f2bf(p0) | ((unsigned)f2bf(p1) << 16);
      w23[j] = (unsigned)f2bf(p2) | ((unsigned)f2bf(p3) << 16);
    }
    float rs = (r0 + r1) + (r2 + r3);
    rs += __shfl_xor(rs, 16);
    rs += __shfl_xor(rs, 32);
    if (skip) {
      li[t] += rs;
    } else {
      li[t] = li[t] * al + rs;
      #pragma unroll
      for (int r = 0; r < 4; ++r) {
        const float alr = __shfl(al, quad * 4 + r);
        #pragma unroll
        for (int jd = 0; jd < 4; ++jd) octx[t][jd][r] *= alr;
      }
    }
    #pragma unroll
    for (int c = 0; c < 4; ++c) {
      const unsigned a0 = qlo ? w01[2 * c] : w01[2 * c + 1];
      const unsigned a1 = qlo ? w01[2 * c + 1] : w01[2 * c];
      const unsigned b0 = qlo ? w23[2 * c] : w23[2 * c + 1];
      const unsigned b1 = qlo ? w23[2 * c + 1] : w23[2 * c];
      const unsigned r00 = (unsigned)__shfl((int)a0, ps0);
      const unsigned r01 = (unsigned)__shfl((int)a1, ps1);
      const unsigned r10 = (unsigned)__shfl((int)b0, ps0);
      const unsigned r11 = (unsigned)__shfl((int)b1, ps1);
      pf[c].d[0] = qh2 ? r00 : r01;
      pf[c].d[2] = qh2 ? r01 : r00;
      pf[c].d[1] = qh2 ? r10 : r11;
      pf[c].d[3] = qh2 ? r11 : r10;
    }
  };

  auto pv = [&](PFU* pf, f32x4* oc) {
    __builtin_amdgcn_s_setprio(1);
    #pragma unroll
    for (int c = 0; c < 4; ++c) {
      #pragma unroll
      for (int jd = 0; jd < 4; ++jd) {
        const int dd = jd * 16 + l16;
        bf16x8 vf = *(const bf16x8*)(Vs + dd * 128 + (((c * 4 + quad) ^ (dd & 15)) * 8));
        oc[jd] = MFMA16(pf[c].v, vf, oc[jd]);
      }
    }
    __builtin_amdgcn_s_setprio(0);
  };

  stageK(0, 0);
  __builtin_amdgcn_s_waitcnt(0xF70);  // vmcnt(0)
  __syncthreads();

  for (int kt = 0; kt <= qt1; ++kt) {
    const int cur = kt & 1;
    stageV(kt);
    if (kt < qt1) stageK(kt + 1, cur ^ 1);
    const bool both = (kt <= qt0);
    const u16* KsC = Ks[cur];

    PFU pf0[4], pf1[4];
    {
      f32x4 sa[8];
      if (both) {
        qkt(KsC, qf[0], sa);
        smx(sa, 0, kt, qt0, pf0);
      }
      qkt(KsC, qf[1], sa);
      smx(sa, 1, kt, qt1, pf1);
    }

    __builtin_amdgcn_s_waitcnt(0xF70);  // vmcnt(0): Vs (and K prefetch) landed
    __syncthreads();

    if (both) pv(pf0, octx[0]);
    pv(pf1, octx[1]);
    __syncthreads();  // Vs consumed by all waves before next restage
  }

  #pragma unroll
  for (int t = 0; t < 2; ++t) {
    const int qt = t ? qt1 : qt0;
    #pragma unroll
    for (int r = 0; r < 4; ++r) {
      const float lr = __builtin_amdgcn_rcpf(__shfl(li[t], quad * 4 + r));
      const int rowg = qt * 128 + rb + quad * 4 + r;
      #pragma unroll
      for (int jd = 0; jd < 4; ++jd) {
        const int col = h * 64 + jd * 16 + l16;
        ctx[((size_t)b * 2048 + rowg) * 1024 + col] = f2bf(octx[t][jd][r] * lr);
      }
    }
  }
}

// ---------------- launch ----------------
extern "C" void kernel_launch(void* const* d_in, const int* in_sizes, int n_in,
                              void* d_out, int out_size, void* d_ws, size_t ws_size,
                              hipStream_t stream) {
  (void)in_sizes; (void)n_in; (void)out_size; (void)ws_size;
  const float* x      = (const float*)d_in[0];
  const float* ln1_w  = (const float*)d_in[1];
  const float* ln1_b  = (const float*)d_in[2];
  const float* w_qkv  = (const float*)d_in[3];
  const float* b_qkv  = (const float*)d_in[4];
  const float* w_attn = (const float*)d_in[5];
  const float* b_attn = (const float*)d_in[6];
  const float* ln2_w  = (const float*)d_in[7];
  const float* ln2_b  = (const float*)d_in[8];
  const float* w_fc   = (const float*)d_in[9];
  const float* b_fc   = (const float*)d_in[10];
  const float* w_proj = (const float*)d_in[11];
  const float* b_proj = (const float*)d_in[12];
  float* out = (float*)d_out;

  char* ws = (char*)d_ws;
  size_t off = 0;
  auto alloc = [&](size_t n) {
    char* p = ws + off;
    off += (n + 255) & ~(size_t)255;
    return p;
  };
  u16* h1     = (u16*)alloc(4096ull * 1024 * 2);
  u16* wqkvT  = (u16*)alloc(3072ull * 1024 * 2);
  u16* wattnT = (u16*)alloc(1024ull * 1024 * 2);
  u16* wfcT   = (u16*)alloc(4096ull * 1024 * 2);
  u16* wprojT = (u16*)alloc(1024ull * 4096 * 2);
  u16* q      = (u16*)alloc(4096ull * 1024 * 2);
  u16* k      = (u16*)alloc(4096ull * 1024 * 2);
  u16* vT     = (u16*)alloc(4096ull * 1024 * 2);
  u16* ctxb   = (u16*)alloc(4096ull * 1024 * 2);
  float* out1 = (float*)alloc(4096ull * 1024 * 4);
  u16* h2     = (u16*)alloc(4096ull * 1024 * 2);
  u16* fco    = (u16*)alloc(4096ull * 4096 * 2);

  u16* vtmp = ctxb;             // dead until attn; raw V [B,H,T,d]
  float* apP = (float*)fco;     // fco dead until FC: attn-proj split-K partials (32 MB)
  float* projP = (float*)q;     // q..ctxb (32 MB) dead after attn-proj: proj partials

  // fused prologue: 4 weight transposes + ln1 (one launch, was five)
  prep<<<16384, 256, 0, stream>>>(w_qkv, w_attn, w_fc, w_proj, x, ln1_w, ln1_b,
                                  wqkvT, wattnT, wfcT, wprojT, h1);

  gemm256<0><<<dim3(192), 512, 0, stream>>>(h1, wqkvT, b_qkv, nullptr, q, k, vtmp,
                                            4096, 3072, 1024);

  transpose_v<<<dim3(32, 32), 256, 0, stream>>>(vtmp, vT);

  attn<<<dim3(8, 32), 512, 0, stream>>>(q, k, vT, ctxb);

  gemm_bt<4><<<dim3(8, 32, 2), 256, 0, stream>>>(ctxb, wattnT, b_attn, nullptr, apP, nullptr,
                                                 nullptr, nullptr, nullptr, 4096, 1024, 1024, 512);
  reduce2_ln<<<4096, 256, 0, stream>>>(apP, x, b_attn, ln2_w, ln2_b, out1, h2, 4096 * 1024);

  gemm256<2><<<dim3(256), 512, 0, stream>>>(h2, wfcT, b_fc, fco, nullptr, nullptr, nullptr,
                                            4096, 4096, 1024);

  gemm_bt<4><<<dim3(8, 32, 2), 256, 0, stream>>>(fco, wprojT, b_proj, nullptr, projP, nullptr,
                                                 nullptr, nullptr, nullptr, 4096, 1024, 4096, 2048);

  reduce2<<<4096, 256, 0, stream>>>(projP, out1, b_proj, out, 4096 * 1024, 1024);
}